// Round 1
// baseline (6211.601 us; speedup 1.0000x reference)
//
#include <hip/hip_runtime.h>
#include <math.h>

#define T_TOK 1024
#define DIM   2048
#define NHQ   16
#define NHKV  4
#define HD    128
#define QKV_N 3072      // (16+2*4)*128
#define NE    8
#define NF    768
#define EPSF  1e-6f

// ============================= embedding gather =============================
__global__ __launch_bounds__(256) void k_embed(const float* __restrict__ embed,
                                               const int* __restrict__ ids,
                                               float* __restrict__ h) {
    int t = blockIdx.x;
    int id = ids[t];
    const float* src = embed + (size_t)id * DIM;
    float* dst = h + (size_t)t * DIM;
    for (int d = threadIdx.x; d < DIM; d += 256) dst[d] = src[d];
}

// ====================== fused add + RMSNorm ======================
// mode 0: v = h;           resid = v
// mode 1: v = h + resid;   resid = v
// mode 2: v = resid        (h unused)
// out = v * rsqrt(mean(v^2)+eps) * w
__global__ __launch_bounds__(256) void k_add_rmsnorm(const float* __restrict__ h,
                                                     float* __restrict__ resid,
                                                     const float* __restrict__ w,
                                                     float* __restrict__ out, int mode) {
    int t = blockIdx.x;
    int tid = threadIdx.x;
    __shared__ float red[256];
    float v[8];
    float ss = 0.f;
    #pragma unroll
    for (int j = 0; j < 8; j++) {
        int d = tid + j * 256;
        float val;
        if (mode == 0)      val = h[t*DIM + d];
        else if (mode == 1) val = h[t*DIM + d] + resid[t*DIM + d];
        else                val = resid[t*DIM + d];
        if (mode != 2) resid[t*DIM + d] = val;
        v[j] = val;
        ss += val * val;
    }
    red[tid] = ss; __syncthreads();
    for (int s = 128; s > 0; s >>= 1) { if (tid < s) red[tid] += red[tid + s]; __syncthreads(); }
    float rs = rsqrtf(red[0] / (float)DIM + EPSF);
    #pragma unroll
    for (int j = 0; j < 8; j++) {
        int d = tid + j * 256;
        out[t*DIM + d] = v[j] * rs * w[d];
    }
}

// ====================== generic fp32 GEMM: C = A[MxK] @ B[KxN] (+C) =========
// grid: (N/64, M/64), block 256. 64x64 tile, TK=16, 4x4 microtile.
template<int ADD>
__global__ __launch_bounds__(256) void k_gemm(const float* __restrict__ A,
                                              const float* __restrict__ B,
                                              float* __restrict__ C,
                                              int M, int N, int K) {
    __shared__ float As[16][65];
    __shared__ float Bs[16][65];
    int tid = threadIdx.x;
    int n0 = blockIdx.x * 64, m0 = blockIdx.y * 64;
    int tx = tid & 15, ty = tid >> 4;
    float acc[4][4] = {};
    for (int k0 = 0; k0 < K; k0 += 16) {
        for (int i = tid; i < 1024; i += 256) {
            int row = i >> 4, kk = i & 15;
            As[kk][row] = A[(size_t)(m0 + row) * K + k0 + kk];
        }
        for (int i = tid; i < 1024; i += 256) {
            int kk = i >> 6, col = i & 63;
            Bs[kk][col] = B[(size_t)(k0 + kk) * N + n0 + col];
        }
        __syncthreads();
        #pragma unroll
        for (int kk = 0; kk < 16; kk++) {
            float a[4], b[4];
            #pragma unroll
            for (int r = 0; r < 4; r++) a[r] = As[kk][ty*4 + r];
            #pragma unroll
            for (int c = 0; c < 4; c++) b[c] = Bs[kk][tx*4 + c];
            #pragma unroll
            for (int r = 0; r < 4; r++)
                #pragma unroll
                for (int c = 0; c < 4; c++) acc[r][c] += a[r] * b[c];
        }
        __syncthreads();
    }
    for (int r = 0; r < 4; r++) {
        int m = m0 + ty*4 + r;
        for (int c = 0; c < 4; c++) {
            size_t idx = (size_t)m * N + n0 + tx*4 + c;
            C[idx] = (ADD ? C[idx] : 0.f) + acc[r][c];
        }
    }
}

// ====================== per-head q/k RMSNorm + RoPE (in place) ==============
// grid: (T, NHQ+NHKV), block 128
__global__ __launch_bounds__(128) void k_qknorm_rope(float* __restrict__ qkv,
                                                     const float* __restrict__ qw,
                                                     const float* __restrict__ kw,
                                                     const int* __restrict__ pos_ids) {
    int t = blockIdx.x, hh = blockIdx.y, tid = threadIdx.x;
    __shared__ float red[128];
    __shared__ float buf[128];
    float* ptr; const float* w;
    if (hh < NHQ) { ptr = qkv + (size_t)t*QKV_N + hh*HD;            w = qw; }
    else          { ptr = qkv + (size_t)t*QKV_N + NHQ*HD + (hh-NHQ)*HD; w = kw; }
    float v = ptr[tid];
    red[tid] = v * v; __syncthreads();
    for (int s = 64; s > 0; s >>= 1) { if (tid < s) red[tid] += red[tid + s]; __syncthreads(); }
    float rs = rsqrtf(red[0] / (float)HD + EPSF);
    float nv = v * rs * w[tid];
    buf[tid] = nv; __syncthreads();
    float other = (tid < 64) ? -buf[tid + 64] : buf[tid - 64];
    int i = tid & 63;
    float pos = (float)pos_ids[t];
    // inv_freq = 1e6^(-2i/128) = 2^(-(2i/128)*log2(1e6))
    float inv_freq = exp2f(-(float)(2*i) * (19.93156856932417f / 128.f));
    float ang = pos * inv_freq;
    float sn, cs;
    sincosf(ang, &sn, &cs);
    ptr[tid] = nv * cs + other * sn;
}

// ====================== attention: one block per (t, q-head) ================
// scores for a whole row (<=1024 keys) fit in LDS; two-pass softmax.
__global__ __launch_bounds__(256) void k_attn(const float* __restrict__ qkv,
                                              float* __restrict__ out) {
    int t = blockIdx.x, hq = blockIdx.y, tid = threadIdx.x;
    int g = hq >> 2;  // HQ/HKV = 4
    __shared__ float qv[HD];
    __shared__ float sc[T_TOK];
    __shared__ float red[256];
    const float* qp = qkv + (size_t)t*QKV_N + hq*HD;
    if (tid < HD) qv[tid] = qp[tid];
    __syncthreads();
    int nk = t + 1;
    const float scale = 0.08838834764831845f;  // 1/sqrt(128)
    float lm = -1e30f;
    for (int j = tid; j < nk; j += 256) {
        const float* kp = qkv + (size_t)j*QKV_N + NHQ*HD + g*HD;
        float dot = 0.f;
        #pragma unroll 8
        for (int d = 0; d < HD; d++) dot += qv[d] * kp[d];
        dot *= scale;
        sc[j] = dot;
        lm = fmaxf(lm, dot);
    }
    red[tid] = lm; __syncthreads();
    for (int s = 128; s > 0; s >>= 1) { if (tid < s) red[tid] = fmaxf(red[tid], red[tid + s]); __syncthreads(); }
    float m = red[0];
    __syncthreads();
    float ls = 0.f;
    for (int j = tid; j < nk; j += 256) {
        float e = __expf(sc[j] - m);
        sc[j] = e; ls += e;
    }
    red[tid] = ls; __syncthreads();
    for (int s = 128; s > 0; s >>= 1) { if (tid < s) red[tid] += red[tid + s]; __syncthreads(); }
    float inv_l = 1.f / red[0];
    if (tid < HD) {
        const float* vp = qkv + (NHQ + NHKV)*HD + g*HD + tid;
        float acc = 0.f;
        for (int j = 0; j < nk; j++) acc += sc[j] * vp[(size_t)j * QKV_N];
        out[(size_t)t*(NHQ*HD) + hq*HD + tid] = acc * inv_l;
    }
}

// ====================== router: gate logits, softmax, top-2, gather =========
__global__ __launch_bounds__(256) void k_gate(const float* __restrict__ x,
                                              const float* __restrict__ gw,
                                              int* counts, int* etok, int* eslot,
                                              float* ew) {
    int t = blockIdx.x, tid = threadIdx.x;
    float acc[NE] = {};
    for (int d = tid; d < DIM; d += 256) {
        float xv = x[t*DIM + d];
        #pragma unroll
        for (int e = 0; e < NE; e++) acc[e] += xv * gw[d*NE + e];
    }
    __shared__ float red[256];
    __shared__ float logits[NE];
    for (int e = 0; e < NE; e++) {
        red[tid] = acc[e]; __syncthreads();
        for (int s = 128; s > 0; s >>= 1) { if (tid < s) red[tid] += red[tid + s]; __syncthreads(); }
        if (tid == 0) logits[e] = red[0];
        __syncthreads();
    }
    if (tid == 0) {
        int i1 = 0; float m1 = logits[0];
        for (int e = 1; e < NE; e++) if (logits[e] > m1) { m1 = logits[e]; i1 = e; }
        int i2 = -1; float m2 = -1e30f;
        for (int e = 0; e < NE; e++) { if (e == i1) continue; if (logits[e] > m2) { m2 = logits[e]; i2 = e; } }
        // renormalized top-2 softmax weights (full-softmax denominators cancel)
        float e2 = expf(m2 - m1);
        float sum = 1.f + e2;
        float w1 = 1.f / sum, w2 = e2 / sum;
        int s1 = atomicAdd(&counts[i1], 1);
        etok[i1*T_TOK + s1] = t; eslot[i1*T_TOK + s1] = t*2;     ew[i1*T_TOK + s1] = w1;
        int s2 = atomicAdd(&counts[i2], 1);
        etok[i2*T_TOK + s2] = t; eslot[i2*T_TOK + s2] = t*2 + 1; ew[i2*T_TOK + s2] = w2;
    }
}

__global__ void k_zero_counts(int* counts) { if (threadIdx.x < NE) counts[threadIdx.x] = 0; }

// ====================== MoE gate_up GEMM + SiLU*mul =========================
// grid: (NE, NF/32, T/64), block 256. 64 tokens x 32 f-pairs, TK=16.
__global__ __launch_bounds__(256) void k_moe_gu(const float* __restrict__ x,
                                                const float* __restrict__ wgu,
                                                const int* __restrict__ counts,
                                                const int* __restrict__ etok,
                                                float* __restrict__ act) {
    int e = blockIdx.x;
    int f0 = blockIdx.y * 32;
    int i0 = blockIdx.z * 64;
    int n = counts[e];
    if (i0 >= n) return;
    int tid = threadIdx.x;
    int tx = tid & 31, ty = tid >> 5;   // 8 row-groups x 32 cols
    __shared__ float XS[16][65];
    __shared__ float WG[16][33];
    __shared__ float WU[16][33];
    __shared__ int toks[64];
    if (tid < 64) { int i = i0 + tid; toks[tid] = (i < n) ? etok[e*T_TOK + i] : 0; }
    __syncthreads();
    const float* W = wgu + (size_t)e * DIM * (2*NF);
    float accg[8] = {}, accu[8] = {};
    for (int k0 = 0; k0 < DIM; k0 += 16) {
        for (int i = tid; i < 1024; i += 256) {
            int row = i >> 4, kk = i & 15;
            XS[kk][row] = x[(size_t)toks[row]*DIM + k0 + kk];
        }
        for (int i = tid; i < 512; i += 256) {
            int kk = i >> 5, c = i & 31;
            WG[kk][c] = W[(size_t)(k0+kk)*(2*NF) + f0 + c];
            WU[kk][c] = W[(size_t)(k0+kk)*(2*NF) + NF + f0 + c];
        }
        __syncthreads();
        #pragma unroll
        for (int kk = 0; kk < 16; kk++) {
            float wg = WG[kk][tx], wu = WU[kk][tx];
            #pragma unroll
            for (int r = 0; r < 8; r++) {
                float xv = XS[kk][ty*8 + r];
                accg[r] += xv * wg;
                accu[r] += xv * wu;
            }
        }
        __syncthreads();
    }
    for (int r = 0; r < 8; r++) {
        int i = i0 + ty*8 + r;
        if (i < n) {
            float gv = accg[r], uv = accu[r];
            float sg = gv / (1.f + expf(-gv));
            act[(size_t)(e*T_TOK + i)*NF + f0 + tx] = sg * uv;
        }
    }
}

// ====================== MoE down GEMM (weighted, slot-scattered) ============
// grid: (NE, DIM/64, T/64), block 256. 64 tokens x 64 d-cols, TK=16.
__global__ __launch_bounds__(256) void k_moe_down(const float* __restrict__ act,
                                                  const float* __restrict__ wd,
                                                  const int* __restrict__ counts,
                                                  const int* __restrict__ eslot,
                                                  const float* __restrict__ ew,
                                                  float* __restrict__ down) {
    int e = blockIdx.x;
    int n0 = blockIdx.y * 64;
    int i0 = blockIdx.z * 64;
    int n = counts[e];
    if (i0 >= n) return;
    int tid = threadIdx.x;
    int tx = tid & 15, ty = tid >> 4;
    __shared__ float As[16][65];
    __shared__ float Bs[16][65];
    const float* W = wd + (size_t)e * NF * DIM;
    float acc[4][4] = {};
    for (int k0 = 0; k0 < NF; k0 += 16) {
        for (int i = tid; i < 1024; i += 256) {
            int row = i >> 4, kk = i & 15;
            As[kk][row] = act[(size_t)(e*T_TOK + i0 + row)*NF + k0 + kk];
        }
        for (int i = tid; i < 1024; i += 256) {
            int kk = i >> 6, col = i & 63;
            Bs[kk][col] = W[(size_t)(k0+kk)*DIM + n0 + col];
        }
        __syncthreads();
        #pragma unroll
        for (int kk = 0; kk < 16; kk++) {
            float a[4], b[4];
            #pragma unroll
            for (int r = 0; r < 4; r++) a[r] = As[kk][ty*4 + r];
            #pragma unroll
            for (int c = 0; c < 4; c++) b[c] = Bs[kk][tx*4 + c];
            #pragma unroll
            for (int r = 0; r < 4; r++)
                #pragma unroll
                for (int c = 0; c < 4; c++) acc[r][c] += a[r] * b[c];
        }
        __syncthreads();
    }
    for (int r = 0; r < 4; r++) {
        int i = i0 + ty*4 + r;
        if (i < n) {
            int sl = eslot[e*T_TOK + i];
            float wv = ew[e*T_TOK + i];
            for (int c = 0; c < 4; c++)
                down[(size_t)sl*DIM + n0 + tx*4 + c] = wv * acc[r][c];
        }
    }
}

// h[t,d] = down[2t,d] + down[2t+1,d]
__global__ __launch_bounds__(256) void k_combine(const float* __restrict__ down,
                                                 float* __restrict__ h) {
    int idx = blockIdx.x * 256 + threadIdx.x;
    int t = idx >> 11;
    int d = idx & 2047;
    h[idx] = down[(size_t)(t*2)*DIM + d] + down[(size_t)(t*2 + 1)*DIM + d];
}

// ============================================================================
extern "C" void kernel_launch(void* const* d_in, const int* in_sizes, int n_in,
                              void* d_out, int out_size, void* d_ws, size_t ws_size,
                              hipStream_t stream) {
    const float* embed        = (const float*)d_in[0];
    const float* ln1_w        = (const float*)d_in[1];
    const float* qkv_w        = (const float*)d_in[2];
    const float* q_norm_w     = (const float*)d_in[3];
    const float* k_norm_w     = (const float*)d_in[4];
    const float* o_w          = (const float*)d_in[5];
    const float* ln2_w        = (const float*)d_in[6];
    const float* gate_w       = (const float*)d_in[7];
    const float* w_gate_up    = (const float*)d_in[8];
    const float* w_down       = (const float*)d_in[9];
    const float* final_norm_w = (const float*)d_in[10];
    const int*   input_ids    = (const int*)d_in[11];
    const int*   position_ids = (const int*)d_in[12];

    char* ws = (char*)d_ws;
    float* resid    = (float*)ws; ws += (size_t)T_TOK*DIM*4;        // 8 MB
    float* x        = (float*)ws; ws += (size_t)T_TOK*DIM*4;        // 8 MB
    float* qkv      = (float*)ws; ws += (size_t)T_TOK*QKV_N*4;      // 12 MB
    float* attn_out = (float*)ws; ws += (size_t)T_TOK*DIM*4;        // 8 MB
    float* h        = (float*)ws; ws += (size_t)T_TOK*DIM*4;        // 8 MB
    float* down     = (float*)ws; ws += (size_t)T_TOK*2*DIM*4;      // 16 MB
    float* act      = (float*)ws; ws += (size_t)NE*T_TOK*NF*4;      // 24 MB
    int*   counts   = (int*)ws;   ws += 256;
    int*   etok     = (int*)ws;   ws += (size_t)NE*T_TOK*4;
    int*   eslot    = (int*)ws;   ws += (size_t)NE*T_TOK*4;
    float* ew       = (float*)ws; ws += (size_t)NE*T_TOK*4;

    k_embed<<<T_TOK, 256, 0, stream>>>(embed, input_ids, h);

    for (int l = 0; l < 2; l++) {
        k_add_rmsnorm<<<T_TOK, 256, 0, stream>>>(h, resid, ln1_w + l*DIM, x, l == 0 ? 0 : 1);
        k_gemm<0><<<dim3(QKV_N/64, T_TOK/64), 256, 0, stream>>>(
            x, qkv_w + (size_t)l*DIM*QKV_N, qkv, T_TOK, QKV_N, DIM);
        k_qknorm_rope<<<dim3(T_TOK, NHQ + NHKV), 128, 0, stream>>>(
            qkv, q_norm_w + l*HD, k_norm_w + l*HD, position_ids);
        k_attn<<<dim3(T_TOK, NHQ), 256, 0, stream>>>(qkv, attn_out);
        k_gemm<1><<<dim3(DIM/64, T_TOK/64), 256, 0, stream>>>(
            attn_out, o_w + (size_t)l*DIM*DIM, resid, T_TOK, DIM, DIM);
        k_add_rmsnorm<<<T_TOK, 256, 0, stream>>>(nullptr, resid, ln2_w + l*DIM, x, 2);
        k_zero_counts<<<1, 64, 0, stream>>>(counts);
        k_gate<<<T_TOK, 256, 0, stream>>>(x, gate_w + (size_t)l*DIM*NE, counts, etok, eslot, ew);
        k_moe_gu<<<dim3(NE, NF/32, T_TOK/64), 256, 0, stream>>>(
            x, w_gate_up + (size_t)l*NE*DIM*2*NF, counts, etok, act);
        k_moe_down<<<dim3(NE, DIM/64, T_TOK/64), 256, 0, stream>>>(
            act, w_down + (size_t)l*NE*NF*DIM, counts, eslot, ew, down);
        k_combine<<<(T_TOK*DIM)/256, 256, 0, stream>>>(down, h);
    }

    k_add_rmsnorm<<<T_TOK, 256, 0, stream>>>(h, resid, final_norm_w, (float*)d_out, 1);
}